// Round 1
// baseline (446.438 us; speedup 1.0000x reference)
//
#include <hip/hip_runtime.h>
#include <hip/hip_bf16.h>

// Problem constants
constexpr int B  = 2;
constexpr int S  = 2048;
constexpr int E  = 1024;
constexpr int H  = 16;
constexpr int DK = 64;
constexpr int M  = B * S;   // 4096 rows of x

using bf16x8 = __attribute__((ext_vector_type(8))) __bf16;
using f32x4  = __attribute__((ext_vector_type(4))) float;

// Load 8 consecutive fp32 and convert to a bf16x8 MFMA fragment.
__device__ inline bf16x8 cvt_frag(const float* __restrict__ p) {
    float4 f0 = *reinterpret_cast<const float4*>(p);
    float4 f1 = *reinterpret_cast<const float4*>(p + 4);
    bf16x8 r;
    r[0] = (__bf16)f0.x; r[1] = (__bf16)f0.y; r[2] = (__bf16)f0.z; r[3] = (__bf16)f0.w;
    r[4] = (__bf16)f1.x; r[5] = (__bf16)f1.y; r[6] = (__bf16)f1.z; r[7] = (__bf16)f1.w;
    return r;
}

// C = x @ W^T, x:[M,E] fp32, W:[N,E] fp32 (N=1024). MODE: 0=K, 1=V(transposed), 2=Q(cos).
// Output bf16. Tile: 128x128 per block (4 waves, each 32 rows x 128 cols).
template <int MODE>
__global__ __launch_bounds__(256)
void proj_kernel(const float* __restrict__ x, const float* __restrict__ W,
                 const float* __restrict__ theta, __bf16* __restrict__ out) {
    const int lane = threadIdx.x & 63;
    const int w    = threadIdx.x >> 6;
    const int quad = lane >> 4;
    const int l16  = lane & 15;
    const int mbase = blockIdx.y * 128 + w * 32;
    const int nbase = blockIdx.x * 128;

    f32x4 acc[2][8];
    #pragma unroll
    for (int i = 0; i < 2; i++)
        #pragma unroll
        for (int j = 0; j < 8; j++)
            acc[i][j] = f32x4{0.f, 0.f, 0.f, 0.f};

    float th[4];
    if (MODE == 2) {
        #pragma unroll
        for (int j = 0; j < 4; j++) th[j] = theta[j * 16 + l16];
    }

    for (int kk = 0; kk < E; kk += 32) {
        bf16x8 a[2], b[8];
        #pragma unroll
        for (int mt = 0; mt < 2; mt++)
            a[mt] = cvt_frag(x + (long)(mbase + mt * 16 + l16) * E + kk + quad * 8);
        #pragma unroll
        for (int nt = 0; nt < 8; nt++)
            b[nt] = cvt_frag(W + (long)(nbase + nt * 16 + l16) * E + kk + quad * 8);
        #pragma unroll
        for (int mt = 0; mt < 2; mt++)
            #pragma unroll
            for (int nt = 0; nt < 8; nt++)
                acc[mt][nt] = __builtin_amdgcn_mfma_f32_16x16x32_bf16(a[mt], b[nt], acc[mt][nt], 0, 0, 0);
    }

    // Epilogue. C/D layout: row = quad*4 + reg, col = lane&15 (verified m89/m91).
    #pragma unroll
    for (int mt = 0; mt < 2; mt++) {
        const int row0 = mbase + mt * 16 + quad * 4;
        #pragma unroll
        for (int nt = 0; nt < 8; nt++) {
            const int col = nbase + nt * 16 + l16;
            const int h = col >> 6;
            const int d = col & 63;
            #pragma unroll
            for (int r = 0; r < 4; r++) {
                const int row = row0 + r;
                const int bb = row >> 11;      // row / S
                const int s  = row & 2047;     // row % S
                float v = acc[mt][nt][r];
                if (MODE == 2) v = cosf(v + th[nt & 3]) * 0.125f;  // fold 1/sqrt(DK)
                long idx;
                if (MODE == 1) idx = ((long)(bb * H + h) * DK + d) * S + s;  // V: [B,H,DK,S]
                else           idx = ((long)(bb * H + h) * S + s) * DK + d;  // K,Q: [B,H,S,DK]
                out[idx] = (__bf16)v;
            }
        }
    }
}

// Flash attention: grid (S/128, B*H), 256 threads = 4 waves; wave owns 32 q-rows.
// K-tile = 64 columns per iteration. No barriers: P round-trips through a
// per-wave LDS region (m120-verified C-layout -> A-layout transform).
__global__ __launch_bounds__(256)
void attn_kernel(const __bf16* __restrict__ q_ws, const __bf16* __restrict__ k_ws,
                 const __bf16* __restrict__ v_ws, float* __restrict__ out) {
    __shared__ __align__(16) __bf16 p_lds[4][32][64];

    const int lane = threadIdx.x & 63;
    const int w    = threadIdx.x >> 6;
    const int quad = lane >> 4;
    const int l16  = lane & 15;
    const int bh    = blockIdx.y;
    const int qbase = blockIdx.x * 128 + w * 32;

    const __bf16* qp = q_ws + (long)bh * S * DK;
    const __bf16* kp = k_ws + (long)bh * S * DK;
    const __bf16* vp = v_ws + (long)bh * DK * S;  // [DK][S]

    // Q A-frags, loaded once: A[m=l16][k=quad*8+j] (m118/m120-verified layout)
    bf16x8 aq[2][2];
    #pragma unroll
    for (int mt = 0; mt < 2; mt++)
        #pragma unroll
        for (int ks = 0; ks < 2; ks++)
            aq[mt][ks] = *reinterpret_cast<const bf16x8*>(
                qp + (long)(qbase + mt * 16 + l16) * DK + ks * 32 + quad * 8);

    f32x4 o[2][4];
    #pragma unroll
    for (int i = 0; i < 2; i++)
        #pragma unroll
        for (int j = 0; j < 4; j++)
            o[i][j] = f32x4{0.f, 0.f, 0.f, 0.f};
    float mst[2][4], lst[2][4];
    #pragma unroll
    for (int i = 0; i < 2; i++)
        #pragma unroll
        for (int r = 0; r < 4; r++) { mst[i][r] = -1e30f; lst[i][r] = 0.f; }

    for (int kt = 0; kt < S; kt += 64) {
        // ---- S = Q K^T (scaled q already holds 1/sqrt(dk)) ----
        f32x4 sacc[2][4];
        #pragma unroll
        for (int i = 0; i < 2; i++)
            #pragma unroll
            for (int j = 0; j < 4; j++)
                sacc[i][j] = f32x4{0.f, 0.f, 0.f, 0.f};
        #pragma unroll
        for (int ks = 0; ks < 2; ks++) {
            bf16x8 bk[4];  // B[k=quad*8+j][n=l16] = K[sk=n][d=k]
            #pragma unroll
            for (int nt = 0; nt < 4; nt++)
                bk[nt] = *reinterpret_cast<const bf16x8*>(
                    kp + (long)(kt + nt * 16 + l16) * DK + ks * 32 + quad * 8);
            #pragma unroll
            for (int mt = 0; mt < 2; mt++)
                #pragma unroll
                for (int nt = 0; nt < 4; nt++)
                    sacc[mt][nt] = __builtin_amdgcn_mfma_f32_16x16x32_bf16(
                        aq[mt][ks], bk[nt], sacc[mt][nt], 0, 0, 0);
        }
        // ---- online softmax (row = quad*4+r, cols across 16 lanes x 4 nt) ----
        #pragma unroll
        for (int mt = 0; mt < 2; mt++) {
            #pragma unroll
            for (int r = 0; r < 4; r++) {
                float vmax = fmaxf(fmaxf(sacc[mt][0][r], sacc[mt][1][r]),
                                   fmaxf(sacc[mt][2][r], sacc[mt][3][r]));
                #pragma unroll
                for (int off = 1; off < 16; off <<= 1)
                    vmax = fmaxf(vmax, __shfl_xor(vmax, off, 16));
                const float mnew  = fmaxf(mst[mt][r], vmax);
                const float alpha = __expf(mst[mt][r] - mnew);
                mst[mt][r] = mnew;
                float p[4], rsum = 0.f;
                #pragma unroll
                for (int nt = 0; nt < 4; nt++) {
                    p[nt] = __expf(sacc[mt][nt][r] - mnew);
                    rsum += p[nt];
                }
                #pragma unroll
                for (int off = 1; off < 16; off <<= 1)
                    rsum += __shfl_xor(rsum, off, 16);
                lst[mt][r] = lst[mt][r] * alpha + rsum;
                #pragma unroll
                for (int ndt = 0; ndt < 4; ndt++) o[mt][ndt][r] *= alpha;
                #pragma unroll
                for (int nt = 0; nt < 4; nt++)
                    p_lds[w][mt * 16 + quad * 4 + r][nt * 16 + l16] = (__bf16)p[nt];
            }
        }
        // ---- O += P V ----
        #pragma unroll
        for (int ks = 0; ks < 2; ks++) {
            bf16x8 ap[2];
            #pragma unroll
            for (int mt = 0; mt < 2; mt++)
                ap[mt] = *reinterpret_cast<const bf16x8*>(
                    &p_lds[w][mt * 16 + l16][ks * 32 + quad * 8]);
            bf16x8 bv[4];  // B[k=quad*8+j][n=l16] = V[sk=k][d=n] from [DK][S]
            #pragma unroll
            for (int ndt = 0; ndt < 4; ndt++)
                bv[ndt] = *reinterpret_cast<const bf16x8*>(
                    vp + (long)(ndt * 16 + l16) * S + kt + ks * 32 + quad * 8);
            #pragma unroll
            for (int mt = 0; mt < 2; mt++)
                #pragma unroll
                for (int ndt = 0; ndt < 4; ndt++)
                    o[mt][ndt] = __builtin_amdgcn_mfma_f32_16x16x32_bf16(
                        ap[mt], bv[ndt], o[mt][ndt], 0, 0, 0);
        }
    }

    // ---- epilogue: out[b][s][h*64+d] = O / l ----
    const int b = bh >> 4, h = bh & 15;
    #pragma unroll
    for (int mt = 0; mt < 2; mt++) {
        #pragma unroll
        for (int r = 0; r < 4; r++) {
            const int srow = qbase + mt * 16 + quad * 4 + r;
            const float inv = 1.0f / lst[mt][r];
            #pragma unroll
            for (int ndt = 0; ndt < 4; ndt++)
                out[(long)(b * S + srow) * E + h * DK + ndt * 16 + l16] =
                    o[mt][ndt][r] * inv;
        }
    }
}

extern "C" void kernel_launch(void* const* d_in, const int* in_sizes, int n_in,
                              void* d_out, int out_size, void* d_ws, size_t ws_size,
                              hipStream_t stream) {
    const float* x     = (const float*)d_in[0];
    const float* Wk    = (const float*)d_in[1];
    const float* Wv    = (const float*)d_in[2];
    const float* Wq    = (const float*)d_in[3];  // [H,DK,E] == [1024,1024] flat
    const float* theta = (const float*)d_in[4];
    float* out = (float*)d_out;

    // Workspace: q,k,v bf16 buffers (8 MB each, 24 MB total)
    __bf16* q_ws = (__bf16*)d_ws;
    __bf16* k_ws = q_ws + (long)B * H * S * DK;
    __bf16* v_ws = k_ws + (long)B * H * S * DK;

    dim3 blk(256);
    dim3 gp(E / 128, M / 128);  // (8, 32)
    proj_kernel<0><<<gp, blk, 0, stream>>>(x, Wk, nullptr, k_ws);
    proj_kernel<1><<<gp, blk, 0, stream>>>(x, Wv, nullptr, v_ws);
    proj_kernel<2><<<gp, blk, 0, stream>>>(x, Wq, theta, q_ws);

    dim3 ga(S / 128, B * H);    // (16, 32)
    attn_kernel<<<ga, blk, 0, stream>>>(q_ws, k_ws, v_ws, out);
}